// Round 8
// baseline (391.615 us; speedup 1.0000x reference)
//
#include <hip/hip_runtime.h>
#include <hip/hip_bf16.h>

#define B_ 128
#define T_ 512
#define L_ 256

// v_dot2_f32_bf16: D = S0.bf16[0]*S1.bf16[0] + S0.bf16[1]*S1.bf16[1] + S2
__device__ __forceinline__ float dot2bf16(unsigned a, unsigned b, float c) {
    float d;
    asm("v_dot2_f32_bf16 %0, %1, %2, %3" : "=v"(d) : "v"(a), "v"(b), "v"(c));
    return d;
}

__device__ __forceinline__ unsigned short f2bf(float x) {  // RNE f32->bf16
    unsigned u = __builtin_bit_cast(unsigned, x);
    return (unsigned short)((u + 0x7fff + ((u >> 16) & 1)) >> 16);
}

// ---------------------------------------------------------------------------
// Kernel A: ETg[m][l] = bf16(exp(trans[l][m]))  (transposed)
// ---------------------------------------------------------------------------
__global__ __launch_bounds__(256) void k_exptrans(const float* __restrict__ trans,
                                                  unsigned short* __restrict__ ETg) {
    int m = blockIdx.x, l = threadIdx.x;
    ETg[m * L_ + l] = f2bf(__expf(trans[l * L_ + m]));
}

// ---------------------------------------------------------------------------
// Kernel B: labels from one-hot y_true (one wave per row)
// ---------------------------------------------------------------------------
__global__ __launch_bounds__(256) void k_labels(const float* __restrict__ y_true,
                                                int* __restrict__ labels) {
    int wid = threadIdx.x >> 6, lane = threadIdx.x & 63;
    int r = blockIdx.x * 4 + wid;
    const float4* row = (const float4*)(y_true + (size_t)r * L_);
    float4 v = row[lane];
    int loc = -1;
    if (v.x > 0.5f) loc = lane * 4 + 0;
    if (v.y > 0.5f) loc = lane * 4 + 1;
    if (v.z > 0.5f) loc = lane * 4 + 2;
    if (v.w > 0.5f) loc = lane * 4 + 3;
    unsigned long long m = __ballot(loc >= 0);
    int src = __ffsll(m) - 1;
    int lab = __shfl(loc, src, 64);
    if (lane == 0) labels[r] = lab;
}

// ---------------------------------------------------------------------------
// Kernel C: path_score
// ---------------------------------------------------------------------------
__global__ __launch_bounds__(256) void k_path(const float* __restrict__ y_pre,
                                              const float* __restrict__ trans,
                                              const int* __restrict__ labels,
                                              float* __restrict__ path) {
    int b = blockIdx.x, tid = threadIdx.x;
    const int* lb = labels + b * T_;
    float acc = 0.f;
    for (int t = tid; t < T_; t += 256) {
        int l1 = lb[t];
        acc += y_pre[((size_t)b * T_ + t) * L_ + l1];
        if (t + 1 < T_) acc += trans[l1 * L_ + lb[t + 1]];
    }
#pragma unroll
    for (int off = 1; off < 64; off <<= 1) acc += __shfl_xor(acc, off, 64);
    __shared__ float red[4];
    int wid = tid >> 6, lane = tid & 63;
    if (lane == 0) red[wid] = acc;
    __syncthreads();
    if (tid == 0) path[b] = red[0] + red[1] + red[2] + red[3];
}

// ---------------------------------------------------------------------------
// Kernel D: forward recursion, 8-wave 8-way l-split, ET register-resident.
// ROOT CAUSE of rounds 2-7: loops containing asm volatile are NOT unrolled
// by LLVM -> R[r][j] keeps runtime indices -> whole array demoted to scratch
// (round-5 error "tied INDIRECT register inputs" proves it; round-7 VGPR=52
// < the 64 ET regs confirms scratch). Fix: ZERO loops around asm touching R
// — pins and dot-product are macro-expanded with literal indices, so SROA
// keeps R in registers and the volatile pins hold it live across the t-loop.
// Demand ~95 VGPR < 128 budget -> no spill incentive.
// ---------------------------------------------------------------------------
#define PIN4(v) asm volatile("" : "+v"((v).x), "+v"((v).y), "+v"((v).z), "+v"((v).w))

__global__ void __launch_bounds__(512, 2)
k_forward(const float* __restrict__ yp_all,
          const unsigned short* __restrict__ ETg,
          const float* __restrict__ path,
          float* __restrict__ out) {
    int b = blockIdx.x, tid = threadIdx.x;
    int c = tid >> 6;          // wave id = l-chunk [32c, 32c+32)
    int i = tid & 63;          // lane; owned rows {i, i+64, i+128, i+192}
    const float* yp = yp_all + (size_t)b * T_ * L_;

    // ET: 4 rows x 32 l = 16 uint4 = 64 VGPRs (all literal-indexed below)
    uint4 R[4][4];
    {
        const uint4* s0 = (const uint4*)(ETg + (size_t)(i      ) * L_ + 32 * c);
        const uint4* s1 = (const uint4*)(ETg + (size_t)(i +  64) * L_ + 32 * c);
        const uint4* s2 = (const uint4*)(ETg + (size_t)(i + 128) * L_ + 32 * c);
        const uint4* s3 = (const uint4*)(ETg + (size_t)(i + 192) * L_ + 32 * c);
        R[0][0] = s0[0]; R[0][1] = s0[1]; R[0][2] = s0[2]; R[0][3] = s0[3];
        R[1][0] = s1[0]; R[1][1] = s1[1]; R[1][2] = s1[2]; R[1][3] = s1[3];
        R[2][0] = s2[0]; R[2][1] = s2[1]; R[2][2] = s2[2]; R[2][3] = s2[3];
        R[3][0] = s3[0]; R[3][1] = s3[1]; R[3][2] = s3[2]; R[3][3] = s3[3];
    }
    PIN4(R[0][0]); PIN4(R[0][1]); PIN4(R[0][2]); PIN4(R[0][3]);
    PIN4(R[1][0]); PIN4(R[1][1]); PIN4(R[1][2]); PIN4(R[1][3]);
    PIN4(R[2][0]); PIN4(R[2][1]); PIN4(R[2][2]); PIN4(R[2][3]);
    PIN4(R[3][0]); PIN4(R[3][1]); PIN4(R[3][2]); PIN4(R[3][3]);

    __shared__ alignas(16) unsigned short ph[2][L_];   // p (bf16), dbuf
    __shared__ float pj[L_ * 9];                       // partials, stride 9
    __shared__ float red[8];
    __shared__ float nmr[2];                           // sampled normalizer

    const bool owner = tid < L_;   // waves 0-3 own one state each
    const int m = tid;

    float s = 0.f, emit = 0.f, emit1 = 0.f;
    if (owner) s = yp[m];          // s_0 = y_pre[b,0,:]

    {   // exact initial max over 256 states (once)
        float v = owner ? s : -3.4e38f;
#pragma unroll
        for (int off = 1; off < 64; off <<= 1) v = fmaxf(v, __shfl_xor(v, off, 64));
        if (i == 0) red[c] = v;
        __syncthreads();
        if (tid == 0) {
            float M = fmaxf(fmaxf(red[0], red[1]), fmaxf(red[2], red[3]));
            nmr[0] = M; nmr[1] = M;
        }
        __syncthreads();
    }

    if (owner) {
        emit  = yp[(size_t)1 * L_ + m];   // E(1)
        emit1 = yp[(size_t)2 * L_ + m];   // E(2)
    }

    for (int t = 1; t < T_; ++t) {
        // ---- phase A (owners): normalize + publish p ----
        float N = 0.f, emit2 = 0.f;
        if (owner) {
            N = nmr[t & 1];                               // s_{t-2}[0] sample
            int tpf = (t + 2 <= T_ - 1) ? (t + 2) : (T_ - 1);
            emit2 = yp[(size_t)tpf * L_ + m];             // E(t+2)
            ph[t & 1][m] = f2bf(__expf(s - N));
        }
        __syncthreads();                   // barrier 1: p visible

        // ---- phase B (all 512): partial dots over own 32-l-chunk ----
        const uint4* P = ((const uint4*)&ph[t & 1][0]) + (c << 2);
        float a0=0,a1=0,a2=0,a3=0,b0=0,b1=0,b2=0,b3=0;
#define DOTJ(jj) { uint4 Pv = P[jj]; \
        a0 = dot2bf16(Pv.x, R[0][jj].x, a0); b0 = dot2bf16(Pv.y, R[0][jj].y, b0); \
        a0 = dot2bf16(Pv.z, R[0][jj].z, a0); b0 = dot2bf16(Pv.w, R[0][jj].w, b0); \
        a1 = dot2bf16(Pv.x, R[1][jj].x, a1); b1 = dot2bf16(Pv.y, R[1][jj].y, b1); \
        a1 = dot2bf16(Pv.z, R[1][jj].z, a1); b1 = dot2bf16(Pv.w, R[1][jj].w, b1); \
        a2 = dot2bf16(Pv.x, R[2][jj].x, a2); b2 = dot2bf16(Pv.y, R[2][jj].y, b2); \
        a2 = dot2bf16(Pv.z, R[2][jj].z, a2); b2 = dot2bf16(Pv.w, R[2][jj].w, b2); \
        a3 = dot2bf16(Pv.x, R[3][jj].x, a3); b3 = dot2bf16(Pv.y, R[3][jj].y, b3); \
        a3 = dot2bf16(Pv.z, R[3][jj].z, a3); b3 = dot2bf16(Pv.w, R[3][jj].w, b3); }
        DOTJ(0) DOTJ(1) DOTJ(2) DOTJ(3)
#undef DOTJ
        pj[(i      ) * 9 + c] = a0 + b0;
        pj[(i +  64) * 9 + c] = a1 + b1;
        pj[(i + 128) * 9 + c] = a2 + b2;
        pj[(i + 192) * 9 + c] = a3 + b3;
        __syncthreads();                   // barrier 2: partials visible

        // ---- phase C (owners): combine 8 partials, advance state ----
        if (owner) {
            const float* q = &pj[m * 9];
            float sum = ((q[0] + q[1]) + (q[2] + q[3]))
                      + ((q[4] + q[5]) + (q[6] + q[7]));
            s = N + __logf(sum) + emit;
            emit = emit1; emit1 = emit2;
            if (tid == 0) nmr[t & 1] = s;  // sample for step t+2
        }
    }

    // ---- final logsumexp over m ----
    __syncthreads();
    {
        float v = owner ? s : -3.4e38f;
#pragma unroll
        for (int off = 1; off < 64; off <<= 1) v = fmaxf(v, __shfl_xor(v, off, 64));
        if (i == 0) red[c] = v;
    }
    __syncthreads();
    float M = fmaxf(fmaxf(red[0], red[1]), fmaxf(red[2], red[3]));
    float e = owner ? __expf(s - M) : 0.f;
    float v = e;
#pragma unroll
    for (int off = 1; off < 64; off <<= 1) v += __shfl_xor(v, off, 64);
    __syncthreads();   // protect red[] reuse
    if (i == 0) red[c] = v;
    __syncthreads();
    if (tid == 0)
        out[b] = M + __logf((red[0] + red[1]) + (red[2] + red[3])) - path[b];
}

// ---------------------------------------------------------------------------
extern "C" void kernel_launch(void* const* d_in, const int* in_sizes, int n_in,
                              void* d_out, int out_size, void* d_ws, size_t ws_size,
                              hipStream_t stream) {
    const float* y_true = (const float*)d_in[0];
    const float* y_pre  = (const float*)d_in[1];
    const float* trans  = (const float*)d_in[2];
    float* out = (float*)d_out;

    char* ws = (char*)d_ws;
    unsigned short* ETg = (unsigned short*)ws;            // 128 KiB
    int* labels = (int*)(ws + 131072);                    // 256 KiB
    float* path = (float*)(ws + 131072 + 262144);         // 512 B

    hipLaunchKernelGGL(k_exptrans, dim3(L_), dim3(L_), 0, stream, trans, ETg);
    hipLaunchKernelGGL(k_labels, dim3(B_ * T_ / 4), dim3(256), 0, stream, y_true, labels);
    hipLaunchKernelGGL(k_path, dim3(B_), dim3(256), 0, stream, y_pre, trans, labels, path);
    hipLaunchKernelGGL(k_forward, dim3(B_), dim3(512), 0, stream, y_pre, ETg, path, out);
}